// Round 9
// baseline (2462.813 us; speedup 1.0000x reference)
//
#include <hip/hip_runtime.h>
#include <hip/hip_bf16.h>
#include <cmath>

using bf16 = __hip_bfloat16;
typedef __attribute__((ext_vector_type(8))) short short8;
typedef __attribute__((ext_vector_type(4))) float floatx4;

__device__ __forceinline__ float bu2f(ushort u) { return __uint_as_float((unsigned)u << 16); }
__device__ __forceinline__ ushort f2bu(float f) {
  union { bf16 b; ushort u; } cv; cv.b = __float2bfloat16(f); return cv.u;
}
__device__ __forceinline__ void gl_lds16(const ushort* g, ushort* l) {
  __builtin_amdgcn_global_load_lds((const __attribute__((address_space(1))) unsigned*)g,
                                   (__attribute__((address_space(3))) unsigned*)l, 16, 0, 0);
}
// tanh-form GELU via hw exp; |err vs erf-GELU| ~2e-4, below bf16 output quantization
__device__ __forceinline__ float fast_gelu(float x) {
  float z = 0.7978845608028654f * (x + 0.044715f * x * x * x);
  z = fmaxf(fminf(z, 10.f), -10.f);
  float e = __expf(2.f * z);
  float t = (e - 1.f) / (e + 1.f);
  return 0.5f * x * (1.f + t);
}

static constexpr int kT   = 4096;
static constexpr int kDim = 1024;
static constexpr float kScale   = 0.08838834764831845f;  // 1/sqrt(128)
static constexpr float kSelfVal = -5.0e4f;

// ---------------- dtype detector: bf16 vs fp32 inputs ----------------
__device__ __forceinline__ int sane_v(float f) { float a = fabsf(f); return (a > 1e-4f && a < 1e4f) ? 1 : 0; }

__global__ __launch_bounds__(256) void k_detect(const unsigned* __restrict__ x, int* __restrict__ flag) {
  __shared__ int cnt;
  int tid = threadIdx.x;
  if (tid == 0) cnt = 0;
  __syncthreads();
  int my = 0;
  const uint4* p = (const uint4*)x;
  for (int q = 0; q < 16; q++) {
    uint4 u = p[tid * 16 + q];
    my += sane_v(__uint_as_float(u.x << 16)) + sane_v(__uint_as_float(u.x & 0xffff0000u));
    my += sane_v(__uint_as_float(u.y << 16)) + sane_v(__uint_as_float(u.y & 0xffff0000u));
    my += sane_v(__uint_as_float(u.z << 16)) + sane_v(__uint_as_float(u.z & 0xffff0000u));
    my += sane_v(__uint_as_float(u.w << 16)) + sane_v(__uint_as_float(u.w & 0xffff0000u));
  }
  atomicAdd(&cnt, my);
  __syncthreads();
  if (tid == 0) flag[0] = (cnt >= 24576) ? 1 : 0;
}

__global__ __launch_bounds__(256) void k_cvt(const int* __restrict__ flag, const void* __restrict__ src,
                                             ushort* __restrict__ dst, int n) {
  int i = blockIdx.x * 256 + threadIdx.x;
  if (i >= n) return;
  dst[i] = (*flag) ? ((const ushort*)src)[i] : f2bu(((const float*)src)[i]);
}

__global__ __launch_bounds__(256) void k_init_any(const int* __restrict__ flag, const void* __restrict__ x,
                                                  float* __restrict__ x1, float* __restrict__ x2) {
  int i = blockIdx.x * 1024 + threadIdx.x * 4;
  float4 f;
  if (*flag) {
    ushort4 u = *(const ushort4*)((const ushort*)x + i);
    f.x = bu2f(u.x); f.y = bu2f(u.y); f.z = bu2f(u.z); f.w = bu2f(u.w);
  } else {
    f = *(const float4*)((const float*)x + i);
  }
  *(float4*)(x1 + i) = f;
  *(float4*)(x2 + i) = f;
}

__global__ __launch_bounds__(256) void k_final_any(const int* __restrict__ flag, const float* __restrict__ x1,
                                                   const float* __restrict__ x2, void* __restrict__ out) {
  int i = blockIdx.x * 1024 + threadIdx.x * 4;
  float4 a = *(const float4*)(x1 + i);
  float4 b = *(const float4*)(x2 + i);
  float4 s; s.x = a.x + b.x; s.y = a.y + b.y; s.z = a.z + b.z; s.w = a.w + b.w;
  if (*flag) {
    ushort4 u; u.x = f2bu(s.x); u.y = f2bu(s.y); u.z = f2bu(s.z); u.w = f2bu(s.w);
    *(ushort4*)((ushort*)out + i) = u;
  } else {
    *(float4*)((float*)out + i) = s;
  }
}

// ---------------- layernorm: fp32 in -> bf16 out ----------------
__global__ __launch_bounds__(256) void k_ln(const float* __restrict__ x, const ushort* __restrict__ g,
                                            const ushort* __restrict__ be, ushort* __restrict__ out) {
  __shared__ float ws[4], ws2[4];
  int row = blockIdx.x, tid = threadIdx.x;
  const float* xr = x + (size_t)row * kDim + tid * 4;
  float4 v = *(const float4*)xr;
  float s  = v.x + v.y + v.z + v.w;
  float s2 = v.x*v.x + v.y*v.y + v.z*v.z + v.w*v.w;
  #pragma unroll
  for (int off = 32; off; off >>= 1) { s += __shfl_down(s, off); s2 += __shfl_down(s2, off); }
  int wave = tid >> 6, lane = tid & 63;
  if (lane == 0) { ws[wave] = s; ws2[wave] = s2; }
  __syncthreads();
  s  = ws[0] + ws[1] + ws[2] + ws[3];
  s2 = ws2[0] + ws2[1] + ws2[2] + ws2[3];
  float mean = s * (1.f/1024.f);
  float var  = fmaxf(s2 * (1.f/1024.f) - mean*mean, 0.f);
  float rstd = rsqrtf(var + 1e-5f);
  int cb = tid * 4;
  ushort* o = out + (size_t)row * kDim + cb;
  o[0] = f2bu((v.x - mean) * rstd * bu2f(g[cb+0]) + bu2f(be[cb+0]));
  o[1] = f2bu((v.y - mean) * rstd * bu2f(g[cb+1]) + bu2f(be[cb+1]));
  o[2] = f2bu((v.z - mean) * rstd * bu2f(g[cb+2]) + bu2f(be[cb+2]));
  o[3] = f2bu((v.w - mean) * rstd * bu2f(g[cb+3]) + bu2f(be[cb+3]));
}

// ---------------- dual-dtype weight transpose: in[K,N] -> out[N,K] ----------------
__global__ __launch_bounds__(256) void k_transpose2(const int* __restrict__ flag, const void* __restrict__ src_bf,
                                                    const void* __restrict__ src_f, ushort* __restrict__ out,
                                                    int K, int N) {
  __shared__ ushort tile[32][33];
  int isbf = *flag;
  int nb = blockIdx.x * 32, kb = blockIdx.y * 32;
  int tx = threadIdx.x & 31, ty = threadIdx.x >> 5;
  for (int r = ty; r < 32; r += 8) {
    size_t idx = (size_t)(kb + r) * N + nb + tx;
    tile[r][tx] = isbf ? ((const ushort*)src_bf)[idx] : f2bu(((const float*)src_f)[idx]);
  }
  __syncthreads();
  for (int r = ty; r < 32; r += 8) out[(size_t)(nb + r) * K + kb + tx] = tile[tx][r];
}

// ---------------- rot transpose: rot[k=128][n=128] -> rotT[n=128][k=128] ----------------
__global__ __launch_bounds__(256) void k_rot_t(const ushort* __restrict__ rot, ushort* __restrict__ rotT) {
  int tid = threadIdx.x;
  for (int idx = tid; idx < 16384; idx += 256) {
    int n = idx >> 7, k = idx & 127;
    rotT[idx] = rot[k * 128 + n];
  }
}

// ---------------- k_gemm7: 256x256 / 2 LDS dbuf / 2 blocks-per-CU (W1, mode-2 only) ----------------
// 512 thr = 8 waves (2M x 4N), wave tile 128x64 (best FLOP/LDS-byte ratio measured:
// 43.7 vs 32 for 64x64). LDS: 2 buffers x (A 16KB + B 16KB) = 64 KB -> 2 blocks/CU;
// __launch_bounds__(512,4) pins VGPR <= 128 (k_gemm5<8> fit exactly 128 with same
// register demand). m97/m114 mechanism: the vmcnt(0) drain before each barrier is
// covered by the co-resident block; cross-block overlap is what buys 37%+ MfmaUtil,
// more than any 1-block/CU source schedule (rounds 3-8 all plateaued at 25-29%).
// Phase kt: { 12 ds_read_b128 (buf kt&1) | stage kt+1 (4 gl_lds -> buf (kt+1)&1)
//   | setprio + 32 MFMA } -> lgkmcnt(0) -> vmcnt(0) -> s_barrier -> fence.
// WAR: stage target (kt+1)&1 was read in phase kt-1 and lgkm-drained before that
// phase's barrier; stage issued after it. RAW: vmcnt(0) lands tile kt+1; barrier
// publishes. Tail stage re-reads the current tile into the dead buffer (harmless).
// Swizzle: LDS slot s of row r holds global chunk s^((r>>1)&3) (source-side XOR);
// reads recover with the same XOR; quarter-wave aliasing 2-way = free.
// Epilogue: two-half LDS-bounce (waves with wm==h write rows [128h,128h+128) of C
// into the 64KB bounce; all 512 threads then store 128 rows coalesced).
__global__ __launch_bounds__(512, 4) void k_gemm7(const ushort* __restrict__ A, const ushort* __restrict__ Bt,
                                                  const ushort* __restrict__ bias, ushort* __restrict__ Cb,
                                                  int M, int N, int K) {
  __shared__ alignas(16) ushort SAu[2 * 256 * 32];   // 32 KB
  __shared__ alignas(16) ushort SBu[2 * 256 * 32];   // 32 KB
  const int tid  = threadIdx.x;
  const int lane = tid & 63, wave = tid >> 6;
  const int lr = lane & 15, g = lane >> 4;
  const int wm = wave >> 2, wn = wave & 3;

  // XCD-aware bijective block swizzle (nwg = 512, % 8 == 0)
  const int nbx = gridDim.x;
  const int nwg = nbx * gridDim.y;
  const int bid = blockIdx.y * nbx + blockIdx.x;
  const int swz = (bid & 7) * (nwg >> 3) + (bid >> 3);
  const int m0 = (swz / nbx) * 256;
  const int n0 = (swz % nbx) * 256;
  const int NT = K >> 5;

  // per-thread staging sources (source col-chunk pre-swizzled, LDS dest linear)
  const ushort* srcA[2];
  const ushort* srcB[2];
  #pragma unroll
  for (int j = 0; j < 2; j++) {
    int chunk = wave * 128 + j * 64 + lane;          // 0..1023
    int row = chunk >> 2, c = chunk & 3;
    int cs = c ^ ((row >> 1) & 3);
    srcA[j] = A  + (size_t)(m0 + row) * K + cs * 8;
    srcB[j] = Bt + (size_t)(n0 + row) * K + cs * 8;
  }

  // fragment read offsets (loop-invariant; ushort units)
  int offA[8], offB[4];
  #pragma unroll
  for (int mi = 0; mi < 8; mi++) {
    int row = wm * 128 + mi * 16 + lr;
    offA[mi] = row * 32 + ((g ^ ((row >> 1) & 3)) * 8);
  }
  #pragma unroll
  for (int ni = 0; ni < 4; ni++) {
    int row = wn * 64 + ni * 16 + lr;
    offB[ni] = row * 32 + ((g ^ ((row >> 1) & 3)) * 8);
  }

  floatx4 acc[8][4];
  #pragma unroll
  for (int mi = 0; mi < 8; mi++)
    #pragma unroll
    for (int ni = 0; ni < 4; ni++) acc[mi][ni] = (floatx4){0.f, 0.f, 0.f, 0.f};

  // prologue: stage K-tile 0 into buf 0
  #pragma unroll
  for (int j = 0; j < 2; j++) {
    gl_lds16(srcA[j], SAu + (wave * 128 + j * 64) * 8);
    gl_lds16(srcB[j], SBu + (wave * 128 + j * 64) * 8);
  }
  asm volatile("s_waitcnt vmcnt(0)" ::: "memory");
  __builtin_amdgcn_s_barrier();
  asm volatile("" ::: "memory");

  for (int kt = 0; kt < NT; kt++) {
    const ushort* sa = SAu + (kt & 1) * 8192;
    const ushort* sb = SBu + (kt & 1) * 8192;
    const int pb = (kt + 1) & 1;
    const int kp = ((kt + 1 < NT) ? (kt + 1) : kt) * 32;   // tail: dead-buffer re-read

    // fragment reads (buf kt&1; validated by previous phase's vmcnt(0)+barrier)
    short8 a[8], b[4];
    #pragma unroll
    for (int mi = 0; mi < 8; mi++) a[mi] = *(const short8*)&sa[offA[mi]];
    #pragma unroll
    for (int ni = 0; ni < 4; ni++) b[ni] = *(const short8*)&sb[offB[ni]];

    // stage tile kt+1 into the other (dead, lgkm-drained) buffer
    #pragma unroll
    for (int j = 0; j < 2; j++) {
      gl_lds16(srcA[j] + kp, SAu + pb * 8192 + (wave * 128 + j * 64) * 8);
      gl_lds16(srcB[j] + kp, SBu + pb * 8192 + (wave * 128 + j * 64) * 8);
    }

    // MFMA cluster (compiler interleaves reads/MFMA with fine lgkmcnt)
    __builtin_amdgcn_s_setprio(1);
    #pragma unroll
    for (int mi = 0; mi < 8; mi++)
      #pragma unroll
      for (int ni = 0; ni < 4; ni++)
        acc[mi][ni] = __builtin_amdgcn_mfma_f32_16x16x32_bf16(a[mi], b[ni], acc[mi][ni], 0, 0, 0);
    __builtin_amdgcn_s_setprio(0);

    asm volatile("s_waitcnt lgkmcnt(0)" ::: "memory");   // own reads drained (WAR)
    asm volatile("s_waitcnt vmcnt(0)" ::: "memory");     // tile kt+1 landed (RAW)
    __builtin_amdgcn_s_barrier();
    asm volatile("" ::: "memory");
  }

  __syncthreads();

  // two-half LDS-bounce epilogue: gelu(val+bias) -> bf16, coalesced dwordx4 stores.
  // Bounce area = 64 KB = 128 rows x 256 cols bf16 (rows 0-63 in SAu, 64-127 in SBu).
  const int hi4 = (lane >> 4) * 4;
  #pragma unroll
  for (int h = 0; h < 2; h++) {
    if (wm == h) {
      #pragma unroll
      for (int mi = 0; mi < 8; mi++) {
        #pragma unroll
        for (int ni = 0; ni < 4; ni++) {
          int colw = wn * 64 + ni * 16 + lr;            // 0..255
          float bv = bu2f(bias[n0 + colw]);
          #pragma unroll
          for (int q = 0; q < 4; q++) {
            int rl = mi * 16 + hi4 + q;                  // 0..127
            ushort* rowp = (rl < 64) ? (SAu + rl * 256) : (SBu + (rl - 64) * 256);
            rowp[(((colw >> 3) ^ (rl & 7)) * 8) + (colw & 7)] = f2bu(fast_gelu(acc[mi][ni][q] + bv));
          }
        }
      }
    }
    __syncthreads();
    {
      const int j = tid & 31;        // 32 x 8 elems = 256 cols
      const int rsub = tid >> 5;     // 0..15
      #pragma unroll
      for (int p = 0; p < 8; p++) {
        int row = p * 16 + rsub;     // 0..127
        const ushort* rowp = (row < 64) ? (SAu + row * 256) : (SBu + (row - 64) * 256);
        short8 v = *(const short8*)&rowp[((j ^ (row & 7)) * 8)];
        *(short8*)&Cb[(size_t)(m0 + h * 128 + row) * N + n0 + j * 8] = v;
      }
    }
    __syncthreads();
  }
  (void)M;
}

// ---------------- k_gemm6: occupancy-first pipelined GEMM (128^2, 3 blocks/CU) ----------------
// (unchanged from round 8; used for the N=1024 shapes and W2)
__global__ __launch_bounds__(256, 3) void k_gemm6(const ushort* __restrict__ A, const ushort* __restrict__ Bt,
                                                  const ushort* __restrict__ bias, float* __restrict__ Cf,
                                                  ushort* __restrict__ Cb, ushort* __restrict__ Cb2,
                                                  int M, int N, int K, int mode) {
  __shared__ alignas(16) ushort SAu[3 * 128 * 32];   // 24 KB
  __shared__ alignas(16) ushort SBu[3 * 128 * 32];   // 24 KB
  const int tid  = threadIdx.x;
  const int lane = tid & 63, wave = tid >> 6;        // 4 waves
  const int lr = lane & 15, g = lane >> 4;
  const int wm = wave >> 1, wn = wave & 1;

  // XCD-aware bijective block swizzle (all grids here have nwg % 8 == 0)
  const int nbx = gridDim.x;
  const int nwg = nbx * gridDim.y;
  const int bid = blockIdx.y * nbx + blockIdx.x;
  const int swz = (bid & 7) * (nwg >> 3) + (bid >> 3);
  const int m0 = (swz / nbx) * 128;
  const int n0 = (swz % nbx) * 128;
  const int NT = K >> 5;

  // per-thread staging sources (source col-chunk pre-swizzled, LDS dest linear)
  const ushort* srcA[2];
  const ushort* srcB[2];
  #pragma unroll
  for (int j = 0; j < 2; j++) {
    int chunk = wave * 128 + j * 64 + lane;          // 0..511
    int row = chunk >> 2, c = chunk & 3;
    int cs = c ^ ((row >> 1) & 3);
    srcA[j] = A  + (size_t)(m0 + row) * K + cs * 8;
    srcB[j] = Bt + (size_t)(n0 + row) * K + cs * 8;
  }

  // fragment read offsets (row&7 == lr&7 since wm*64, mi*16 are multiples of 8)
  int offA[4], offB[4];
  #pragma unroll
  for (int mi = 0; mi < 4; mi++) {
    int row = wm * 64 + mi * 16 + lr;
    offA[mi] = row * 32 + ((g ^ ((row >> 1) & 3)) * 8);
  }
  #pragma unroll
  for (int ni = 0; ni < 4; ni++) {
    int row = wn * 64 + ni * 16 + lr;
    offB[ni] = row * 32 + ((g ^ ((row >> 1) & 3)) * 8);
  }

  floatx4 acc[4][4];
  #pragma unroll
  for (int mi = 0; mi < 4; mi++)
    #pragma unroll
    for (int ni = 0; ni < 4; ni++) acc[mi][ni] = (floatx4){0.f, 0.f, 0.f, 0.f};

  // prologue: stage K-tiles 0,1
  #pragma unroll
  for (int p = 0; p < 2; p++) {
    #pragma unroll
    for (int j = 0; j < 2; j++) {
      gl_lds16(srcA[j] + p * 32, SAu + p * 4096 + (wave * 128 + j * 64) * 8);
      gl_lds16(srcB[j] + p * 32, SBu + p * 4096 + (wave * 128 + j * 64) * 8);
    }
  }
  asm volatile("s_waitcnt vmcnt(4)" ::: "memory");   // tile 0 landed
  __builtin_amdgcn_s_barrier();
  asm volatile("" ::: "memory");

  int cur = 0;
  for (int kt = 0; kt < NT; kt++) {
    const ushort* sa = SAu + cur * 4096;
    const ushort* sb = SBu + cur * 4096;
    int pb = cur + 2; if (pb >= 3) pb -= 3;
    const int kp = ((kt + 2 < NT) ? (kt + 2) : 0) * 32;   // dummy-clamp past NT

    short8 a[4], b[4];
    #pragma unroll
    for (int mi = 0; mi < 4; mi++) a[mi] = *(const short8*)&sa[offA[mi]];
    #pragma unroll
    for (int ni = 0; ni < 4; ni++) b[ni] = *(const short8*)&sb[offB[ni]];

    #pragma unroll
    for (int j = 0; j < 2; j++) {
      gl_lds16(srcA[j] + kp, SAu + pb * 4096 + (wave * 128 + j * 64) * 8);
      gl_lds16(srcB[j] + kp, SBu + pb * 4096 + (wave * 128 + j * 64) * 8);
    }

    __builtin_amdgcn_s_setprio(1);
    #pragma unroll
    for (int mi = 0; mi < 4; mi++)
      #pragma unroll
      for (int ni = 0; ni < 4; ni++)
        acc[mi][ni] = __builtin_amdgcn_mfma_f32_16x16x32_bf16(a[mi], b[ni], acc[mi][ni], 0, 0, 0);
    __builtin_amdgcn_s_setprio(0);

    asm volatile("s_waitcnt lgkmcnt(0)" ::: "memory");
    asm volatile("s_waitcnt vmcnt(4)" ::: "memory");   // tile kt+1 landed; kt+2 in flight
    __builtin_amdgcn_s_barrier();
    asm volatile("" ::: "memory");

    cur = (cur == 2) ? 0 : cur + 1;
  }

  asm volatile("s_waitcnt vmcnt(0)" ::: "memory");
  __syncthreads();

  const int hi4 = (lane >> 4) * 4;

  if (mode == 1) {
    #pragma unroll
    for (int mi = 0; mi < 4; mi++) {
      #pragma unroll
      for (int ni = 0; ni < 4; ni++) {
        int col = n0 + wn * 64 + ni * 16 + lr;
        float bv = bu2f(bias[col]);
        #pragma unroll
        for (int q = 0; q < 4; q++) {
          int r2 = m0 + wm * 64 + mi * 16 + hi4 + q;
          Cf[(size_t)r2 * N + col] += acc[mi][ni][q] + bv;
        }
      }
    }
  } else {
    #pragma unroll
    for (int mi = 0; mi < 4; mi++) {
      #pragma unroll
      for (int ni = 0; ni < 4; ni++) {
        int colw = wn * 64 + ni * 16 + lr;            // 0..127
        float bv = (mode == 2) ? bu2f(bias[n0 + colw]) : 0.f;
        #pragma unroll
        for (int q = 0; q < 4; q++) {
          int rl = wm * 64 + mi * 16 + hi4 + q;       // 0..127
          ushort* rowp = (rl < 96) ? (SBu + rl * 128) : (SAu + (rl - 96) * 128);
          float val = acc[mi][ni][q];
          ushort h = (mode == 2) ? f2bu(fast_gelu(val + bv)) : f2bu(val);
          rowp[(((colw >> 3) ^ (rl & 7)) * 8) + (colw & 7)] = h;
        }
      }
    }
    __syncthreads();
    {
      const int j = tid & 15;
      const int rsub = tid >> 4;     // 0..15
      #pragma unroll
      for (int p = 0; p < 8; p++) {
        int row = p * 16 + rsub;
        const ushort* rowp = (row < 96) ? (SBu + row * 128) : (SAu + (row - 96) * 128);
        short8 v = *(const short8*)&rowp[(j ^ (row & 7)) * 8];
        *(short8*)&Cb[(size_t)(m0 + row) * N + n0 + j * 8] = v;
      }
    }
    if (mode == 5) {
      __syncthreads();
      #pragma unroll
      for (int mi = 0; mi < 4; mi++) {
        #pragma unroll
        for (int ni = 0; ni < 4; ni++) {
          int colw = wn * 64 + ni * 16 + lr;
          #pragma unroll
          for (int q = 0; q < 4; q++) {
            int rl = wm * 64 + mi * 16 + hi4 + q;
            ushort* rowp = (rl < 96) ? (SBu + rl * 128) : (SAu + (rl - 96) * 128);
            float val = acc[mi][ni][q];
            ushort h = f2bu(val);
            rowp[(((colw >> 3) ^ (rl & 7)) * 8) + (colw & 7)] = f2bu(val - bu2f(h));
          }
        }
      }
      __syncthreads();
      const int j = tid & 15;
      const int rsub = tid >> 4;
      #pragma unroll
      for (int p = 0; p < 8; p++) {
        int row = p * 16 + rsub;
        const ushort* rowp = (row < 96) ? (SBu + row * 128) : (SAu + (row - 96) * 128);
        short8 v = *(const short8*)&rowp[(j ^ (row & 7)) * 8];
        *(short8*)&Cb2[(size_t)(m0 + row) * N + n0 + j * 8] = v;
      }
    }
  }
  (void)M;
}

// ---------------- MFMA bucket: consumes qk hi/lo bf16 planes; in-register first-max argmax ----------------
__global__ __launch_bounds__(256) void k_bucket_mfma(const ushort* __restrict__ qkh, const ushort* __restrict__ qkl,
                                                     const ushort* __restrict__ rotT, int* __restrict__ bkt) {
  __shared__ alignas(16) ushort Bs[128*128];  // rotT [n][k]  32 KB
  __shared__ alignas(16) ushort Ah[64*128];   // Q hi         16 KB
  __shared__ alignas(16) ushort Al[64*128];   // Q lo         16 KB
  const int tid = threadIdx.x;
  const int lane = tid & 63, wave = tid >> 6;
  const int lr = lane & 15, lk = (lane >> 4) * 8;
  const int tt = blockIdx.x * 64;
  const int bh = blockIdx.y;
  const int b = bh >> 3, hh = bh & 7;

  {
    int r = tid >> 2, c0 = (tid & 3) * 32;
    size_t base = ((size_t)(b * kT + tt + r)) * kDim + hh * 128 + c0;
    const uint4* sh = (const uint4*)(qkh + base);
    const uint4* sl = (const uint4*)(qkl + base);
    uint4* dh = (uint4*)&Ah[r * 128 + c0];
    uint4* dl = (uint4*)&Al[r * 128 + c0];
    #pragma unroll
    for (int i = 0; i < 4; i++) { dh[i] = sh[i]; dl[i] = sl[i]; }
  }
  {
    const uint4* src = (const uint4*)rotT;
    uint4* dst = (uint4*)Bs;
    for (int i = tid; i < 2048; i += 256) dst[i] = src[i];
  }
  __syncthreads();

  floatx4 acc[4][2];
  #pragma unroll
  for (int mi = 0; mi < 4; mi++) { acc[mi][0] = (floatx4){0,0,0,0}; acc[mi][1] = (floatx4){0,0,0,0}; }
  #pragma unroll
  for (int ks = 0; ks < 4; ks++) {
    short8 a[4], bb[2];
    #pragma unroll
    for (int ni = 0; ni < 2; ni++) bb[ni] = *(const short8*)&Bs[(wave*32 + ni*16 + lr)*128 + ks*32 + lk];
    #pragma unroll
    for (int mi = 0; mi < 4; mi++) a[mi] = *(const short8*)&Ah[(mi*16 + lr)*128 + ks*32 + lk];
    #pragma unroll
    for (int mi = 0; mi < 4; mi++)
      #pragma unroll
      for (int ni = 0; ni < 2; ni++)
        acc[mi][ni] = __builtin_amdgcn_mfma_f32_16x16x32_bf16(a[mi], bb[ni], acc[mi][ni], 0, 0, 0);
  }
  #pragma unroll
  for (int ks = 0; ks < 4; ks++) {
    short8 a[4], bb[2];
    #pragma unroll
    for (int ni = 0; ni < 2; ni++) bb[ni] = *(const short8*)&Bs[(wave*32 + ni*16 + lr)*128 + ks*32 + lk];
    #pragma unroll
    for (int mi = 0; mi < 4; mi++) a[mi] = *(const short8*)&Al[(mi*16 + lr)*128 + ks*32 + lk];
    #pragma unroll
    for (int mi = 0; mi < 4; mi++)
      #pragma unroll
      for (int ni = 0; ni < 2; ni++)
        acc[mi][ni] = __builtin_amdgcn_mfma_f32_16x16x32_bf16(a[mi], bb[ni], acc[mi][ni], 0, 0, 0);
  }

  #pragma unroll
  for (int mi = 0; mi < 4; mi++) {
    #pragma unroll
    for (int q = 0; q < 4; q++) {
      float v0 = acc[mi][0][q];
      float v1 = acc[mi][1][q];
      float best = v0; int bidx = lr;
      if (v1  > best) { best = v1;  bidx = 16 + lr; }
      if (-v0 > best) { best = -v0; bidx = 32 + lr; }
      if (-v1 > best) { best = -v1; bidx = 48 + lr; }
      #pragma unroll
      for (int m = 1; m <= 8; m <<= 1) {
        float ov = __shfl_xor(best, m);
        int   oi = __shfl_xor(bidx, m);
        if (ov > best || (ov == best && oi < bidx)) { best = ov; bidx = oi; }
      }
      if (lr == 0) {
        int row = mi*16 + ((lane >> 4) & 3)*4 + q;
        bkt[(bh*4 + wave)*4096 + tt + row] = bidx;
      }
    }
  }
}

// ---------------- stable counting sort per (bh,hash) ----------------
__global__ __launch_bounds__(256) void k_sort(const int* __restrict__ bkt, int* __restrict__ st) {
  __shared__ unsigned char  hist[64*256];
  __shared__ unsigned short offs[64*256];
  __shared__ int base[64];
  int tid = threadIdx.x, grp = blockIdx.x;
  const int* bk = bkt + grp * 4096;
  for (int i = tid; i < 64*256; i += 256) hist[i] = 0;
  __syncthreads();
  int myb[16];
  #pragma unroll
  for (int j = 0; j < 16; j++) {
    myb[j] = bk[tid*16 + j];
    hist[myb[j]*256 + tid] += 1;
  }
  __syncthreads();
  if (tid < 64) {
    int run = 0;
    for (int t = 0; t < 256; t++) { offs[tid*256 + t] = (unsigned short)run; run += hist[tid*256 + t]; }
    base[tid] = run;
  }
  __syncthreads();
  if (tid == 0) {
    int run = 0;
    for (int b2 = 0; b2 < 64; b2++) { int c = base[b2]; base[b2] = run; run += c; }
  }
  __syncthreads();
  #pragma unroll
  for (int j = 0; j < 16; j++) {
    int b2 = myb[j];
    int r = 0;
    for (int jj = 0; jj < j; jj++) r += (myb[jj] == b2) ? 1 : 0;
    st[grp*4096 + base[b2] + (int)offs[b2*256 + tid] + r] = tid*16 + j;
  }
}

// ---------------- chunked LSH attention (bf16 qk hi-plane input) ----------------
__global__ __launch_bounds__(256) void k_attn(const ushort* __restrict__ qkh, const ushort* __restrict__ vbuf,
                                              const int* __restrict__ st, ushort* __restrict__ o_r,
                                              float* __restrict__ lse_r) {
  __shared__ alignas(16) ushort KV[128*136];
  __shared__ alignas(16) ushort Ps[64*136];
  __shared__ float rnorm[128];
  __shared__ int   kposs[128];
  __shared__ float red1[64*4];
  __shared__ float red2[64*4];
  __shared__ float lrow[64];

  const int tid = threadIdx.x;
  const int bid = blockIdx.x;
  const int bh = bid >> 8;
  const int c  = bid & 255;
  const int h  = c >> 6;
  const int cprev = (c + 255) & 255;
  const int b  = bh >> 3, hh = bh & 7;
  const int lane = tid & 63, wave = tid >> 6;
  const int lr = lane & 15, lk = (lane >> 4) * 8;

  {
    int j = tid >> 1, half = tid & 1;
    int slot = (j < 64) ? (c*64 + j) : (cprev*64 + (j - 64));
    int pos = st[bh*16384 + slot];
    if (half == 0) kposs[j] = pos;
    const ushort* src = qkh + ((size_t)(b * kT + pos)) * kDim + hh*128 + half*64;
    float ss = 0.f;
    #pragma unroll
    for (int i2 = 0; i2 < 64; i2 += 8) {
      uint4 u = *(const uint4*)(src + i2);
      *(uint4*)&KV[j*136 + half*64 + i2] = u;
      float f0 = bu2f((ushort)(u.x & 0xffffu)), f1 = bu2f((ushort)(u.x >> 16));
      float f2 = bu2f((ushort)(u.y & 0xffffu)), f3 = bu2f((ushort)(u.y >> 16));
      float f4 = bu2f((ushort)(u.z & 0xffffu)), f5 = bu2f((ushort)(u.z >> 16));
      float f6 = bu2f((ushort)(u.w & 0xffffu)), f7 = bu2f((ushort)(u.w >> 16));
      ss += f0*f0 + f1*f1 + f2*f2 + f3*f3 + f4*f4 + f5*f5 + f6*f6 + f7*f7;
    }
    ss += __shfl_xor(ss, 1);
    if (half == 0) rnorm[j] = 1.f / fmaxf(sqrtf(ss), 1e-12f);
  }
  __syncthreads();

  {
    floatx4 acc[4][2];
    #pragma unroll
    for (int mi = 0; mi < 4; mi++) { acc[mi][0] = (floatx4){0,0,0,0}; acc[mi][1] = (floatx4){0,0,0,0}; }
    #pragma unroll
    for (int ks = 0; ks < 4; ks++) {
      short8 a[4], bb[2];
      #pragma unroll
      for (int mi = 0; mi < 4; mi++) a[mi]  = *(const short8*)&KV[(mi*16 + lr)*136 + ks*32 + lk];
      #pragma unroll
      for (int ni = 0; ni < 2; ni++) bb[ni] = *(const short8*)&KV[(wave*32 + ni*16 + lr)*136 + ks*32 + lk];
      #pragma unroll
      for (int mi = 0; mi < 4; mi++)
        #pragma unroll
        for (int ni = 0; ni < 2; ni++)
          acc[mi][ni] = __builtin_amdgcn_mfma_f32_16x16x32_bf16(a[mi], bb[ni], acc[mi][ni], 0, 0, 0);
    }
    #pragma unroll
    for (int mi = 0; mi < 4; mi++) {
      #pragma unroll
      for (int ni = 0; ni < 2; ni++) {
        int col = wave*32 + ni*16 + lr;
        float rn = rnorm[col] * kScale;
        int cpos = kposs[col];
        #pragma unroll
        for (int q = 0; q < 4; q++) {
          int row = mi*16 + (lane >> 4)*4 + q;
          float val = acc[mi][ni][q] * rn;
          if (cpos == kposs[row]) val = kSelfVal;
          Ps[row*136 + col] = f2bu(val);
        }
      }
    }
  }
  __syncthreads();

  {
    int j = tid >> 1, half = tid & 1;
    int pos = kposs[j];
    const ushort* src = vbuf + ((size_t)(b * kT + pos)) * kDim + hh*128 + half*64;
    #pragma unroll
    for (int i2 = 0; i2 < 64; i2 += 8) {
      uint4 u = *(const uint4*)(src + i2);
      int d0 = half*64 + i2;
      KV[(d0+0)*136 + j] = (ushort)(u.x & 0xffffu); KV[(d0+1)*136 + j] = (ushort)(u.x >> 16);
      KV[(d0+2)*136 + j] = (ushort)(u.y & 0xffffu); KV[(d0+3)*136 + j] = (ushort)(u.y >> 16);
      KV[(d0+4)*136 + j] = (ushort)(u.z & 0xffffu); KV[(d0+5)*136 + j] = (ushort)(u.z >> 16);
      KV[(d0+6)*136 + j] = (ushort)(u.w & 0xffffu); KV[(d0+7)*136 + j] = (ushort)(u.w >> 16);
    }
  }

  {
    int i = tid >> 2, part = tid & 3;
    const int jb = part * 32;
    float m = -1e30f;
    for (int j2 = 0; j2 < 32; j2++) m = fmaxf(m, bu2f(Ps[i*136 + jb + j2]));
    red1[i*4 + part] = m;
    __syncthreads();
    m = fmaxf(fmaxf(red1[i*4+0], red1[i*4+1]), fmaxf(red1[i*4+2], red1[i*4+3]));
    float ssum = 0.f;
    for (int j2 = 0; j2 < 32; j2++) {
      float arg = fmaxf(fminf(bu2f(Ps[i*136 + jb + j2]) - m, 0.f), -80.f);
      float p = __expf(arg);
      ssum += p;
      Ps[i*136 + jb + j2] = f2bu(p);
    }
    red2[i*4 + part] = ssum;
    __syncthreads();
    if (part == 0) {
      float l = fmaxf(red2[i*4+0] + red2[i*4+1] + red2[i*4+2] + red2[i*4+3], 1e-20f);
      lrow[i] = 1.f / l;
      lse_r[(size_t)(bh*4 + h)*4096 + kposs[i]] = m + __logf(l);
    }
  }
  __syncthreads();

  {
    floatx4 acc[4][2];
    #pragma unroll
    for (int mi = 0; mi < 4; mi++) { acc[mi][0] = (floatx4){0,0,0,0}; acc[mi][1] = (floatx4){0,0,0,0}; }
    #pragma unroll
    for (int ks = 0; ks < 4; ks++) {
      short8 a[4], bb[2];
      #pragma unroll
      for (int mi = 0; mi < 4; mi++) a[mi]  = *(const short8*)&Ps[(mi*16 + lr)*136 + ks*32 + lk];
      #pragma unroll
      for (int ni = 0; ni < 2; ni++) bb[ni] = *(const short8*)&KV[(wave*32 + ni*16 + lr)*136 + ks*32 + lk];
      #pragma unroll
      for (int mi = 0; mi < 4; mi++)
        #pragma unroll
        for (int ni = 0; ni < 2; ni++)
          acc[mi][ni] = __builtin_amdgcn_mfma_f32_16x16x32_bf16(a[mi], bb[ni], acc[mi][ni], 0, 0, 0);
    }
    #pragma unroll
    for (int mi = 0; mi < 4; mi++) {
      #pragma unroll
      for (int ni = 0; ni < 2; ni++) {
        int d = wave*32 + ni*16 + lr;
        #pragma unroll
        for (int q = 0; q < 4; q++) {
          int row = mi*16 + (lane >> 4)*4 + q;
          float o = acc[mi][ni][q] * lrow[row];
          o_r[((size_t)(bh*4 + h)*4096 + kposs[row])*128 + d] = f2bu(o);
        }
      }
    }
  }
}

// ---------------- combine hash rounds ----------------
__global__ __launch_bounds__(256) void k_combine(const ushort* __restrict__ o_r, const float* __restrict__ lse_r,
                                                 ushort* __restrict__ attnbf) {
  int rid = blockIdx.x * 2 + (threadIdx.x >> 7);
  int d = threadIdx.x & 127;
  int bh = rid >> 12, t = rid & 4095;
  int b = bh >> 3, hh = bh & 7;
  size_t base = (size_t)bh * 16384 + t;
  float l0 = lse_r[base], l1 = lse_r[base + 4096], l2 = lse_r[base + 8192], l3 = lse_r[base + 12288];
  float M = fmaxf(fmaxf(l0, l1), fmaxf(l2, l3));
  float e0 = __expf(fmaxf(fminf(l0 - M, 0.f), -80.f));
  float e1 = __expf(fmaxf(fminf(l1 - M, 0.f), -80.f));
  float e2 = __expf(fmaxf(fminf(l2 - M, 0.f), -80.f));
  float e3 = __expf(fmaxf(fminf(l3 - M, 0.f), -80.f));
  float inv = 1.f / (e0 + e1 + e2 + e3);
  float o = e0 * bu2f(o_r[(base         )*128 + d]) + e1 * bu2f(o_r[(base +  4096)*128 + d])
          + e2 * bu2f(o_r[(base +  8192)*128 + d]) + e3 * bu2f(o_r[(base + 12288)*128 + d]);
  attnbf[((size_t)b * kT + t) * kDim + hh*128 + d] = f2bu(o * inv);
}

extern "C" void kernel_launch(void* const* d_in, const int* in_sizes, int n_in,
                              void* d_out, int out_size, void* d_ws, size_t ws_size,
                              hipStream_t stream) {
  (void)in_sizes; (void)n_in; (void)out_size; (void)ws_size;
  const void* x     = d_in[0];
  const void* ln1_g = d_in[1];
  const void* ln1_b = d_in[2];
  const void* Wqk   = d_in[3];
  const void* Wv    = d_in[4];
  const void* Wo    = d_in[5];
  const void* bo    = d_in[6];
  const void* ln2_g = d_in[7];
  const void* ln2_b = d_in[8];
  const void* W1    = d_in[9];
  const void* b1    = d_in[10];
  const void* W2    = d_in[11];
  const void* b2    = d_in[12];
  const void* rot   = d_in[13];

  char* w = (char*)d_ws;
  int*    flag = (int*)w;    w += 256;
  ushort* prm  = (ushort*)w; w += 131072;
  float* x1  = (float*)w;  w += 33554432;
  float* x2  = (float*)w;  w += 33554432;
  ushort* qkh = (ushort*)w; w += 16777216;
  ushort* qkl = (ushort*)w; w += 16777216;
  ushort* vbb = (ushort*)w; w += 16777216;
  ushort* xbf = (ushort*)w; w += 16777216;
  ushort* orb = (ushort*)w; w += 67108864;
  float* lse = (float*)w;  w += 1048576;
  int*   bkt = (int*)w;    w += 1048576;
  int*   stb = (int*)w;    w += 1048576;
  ushort* wtA = (ushort*)w; w += 2097152;
  ushort* wtB = (ushort*)w; w += 2097152;
  ushort* wtC = (ushort*)w; w += 2097152;
  ushort* wt1 = (ushort*)w; w += 8388608;
  ushort* wt2 = (ushort*)w; w += 8388608;
  ushort* rtT = (ushort*)w; w += 32768;

  ushort* pLN1G = prm + 0;     ushort* pLN1B = prm + 2048;
  ushort* pBO   = prm + 4096;  ushort* pLN2G = prm + 6144;
  ushort* pLN2B = prm + 8192;  ushort* pB1   = prm + 10240;
  ushort* pB2   = prm + 18432; ushort* pROT  = prm + 20480;

  k_detect<<<1, 256, 0, stream>>>((const unsigned*)x, flag);
  k_cvt<<<8,   256, 0, stream>>>(flag, ln1_g, pLN1G, 2048);
  k_cvt<<<8,   256, 0, stream>>>(flag, ln1_b, pLN1B, 2048);
  k_cvt<<<8,   256, 0, stream>>>(flag, bo,    pBO,   2048);
  k_cvt<<<8,   256, 0, stream>>>(flag, ln2_g, pLN2G, 2048);
  k_cvt<<<8,   256, 0, stream>>>(flag, ln2_b, pLN2B, 2048);
  k_cvt<<<32,  256, 0, stream>>>(flag, b1,    pB1,   8192);
  k_cvt<<<8,   256, 0, stream>>>(flag, b2,    pB2,   2048);
  k_cvt<<<128, 256, 0, stream>>>(flag, rot,   pROT,  32768);
  k_init_any<<<8192, 256, 0, stream>>>(flag, x, x1, x2);

  for (int d = 0; d < 2; d++) {
    k_transpose2<<<dim3(32, 32),  256, 0, stream>>>(flag,
        (const char*)Wqk + (size_t)d*1048576*2, (const char*)Wqk + (size_t)d*1048576*4, wtA, 1024, 1024);
    k_transpose2<<<dim3(32, 32),  256, 0, stream>>>(flag,
        (const char*)Wv  + (size_t)d*1048576*2, (const char*)Wv  + (size_t)d*1048576*4, wtB, 1024, 1024);
    k_transpose2<<<dim3(32, 32),  256, 0, stream>>>(flag,
        (const char*)Wo  + (size_t)d*1048576*2, (const char*)Wo  + (size_t)d*1048576*4, wtC, 1024, 1024);
    k_transpose2<<<dim3(128, 32), 256, 0, stream>>>(flag,
        (const char*)W1  + (size_t)d*4194304*2, (const char*)W1  + (size_t)d*4194304*4, wt1, 1024, 4096);
    k_transpose2<<<dim3(32, 128), 256, 0, stream>>>(flag,
        (const char*)W2  + (size_t)d*4194304*2, (const char*)W2  + (size_t)d*4194304*4, wt2, 4096, 1024);
    k_rot_t<<<1, 256, 0, stream>>>(pROT + (size_t)d * 16384, rtT);

    k_ln<<<8192, 256, 0, stream>>>(x2, pLN1G + d*1024, pLN1B + d*1024, xbf);
    k_gemm6<<<dim3(8, 64), 256, 0, stream>>>(xbf, wtA, nullptr, nullptr, qkh, qkl, 8192, 1024, 1024, 5);
    k_gemm6<<<dim3(8, 64), 256, 0, stream>>>(xbf, wtB, nullptr, nullptr, vbb, nullptr, 8192, 1024, 1024, 3);
    k_bucket_mfma<<<dim3(64, 16), 256, 0, stream>>>(qkh, qkl, rtT, bkt);
    k_sort<<<64, 256, 0, stream>>>(bkt, stb);
    k_attn<<<4096, 256, 0, stream>>>(qkh, vbb, stb, orb, lse);
    k_combine<<<32768, 256, 0, stream>>>(orb, lse, xbf);
    k_gemm6<<<dim3(8, 64), 256, 0, stream>>>(xbf, wtC, pBO + d*1024, x1, nullptr, nullptr, 8192, 1024, 1024, 1);
    k_ln<<<8192, 256, 0, stream>>>(x1, pLN2G + d*1024, pLN2B + d*1024, xbf);
    k_gemm7<<<dim3(16, 32), 512, 0, stream>>>(xbf, wt1, pB1 + d*4096, orb, 8192, 4096, 1024);
    k_gemm6<<<dim3(8, 64), 256, 0, stream>>>(orb, wt2, pB2 + d*1024, x2, nullptr, nullptr, 8192, 1024, 4096, 1);
  }
  k_final_any<<<8192, 256, 0, stream>>>(flag, x1, x2, d_out);
}

// Round 10
// 1104.353 us; speedup vs baseline: 2.2301x; 2.2301x over previous
//
#include <hip/hip_runtime.h>
#include <hip/hip_bf16.h>
#include <cmath>

using bf16 = __hip_bfloat16;
typedef __attribute__((ext_vector_type(8))) short short8;
typedef __attribute__((ext_vector_type(4))) float floatx4;

__device__ __forceinline__ float bu2f(ushort u) { return __uint_as_float((unsigned)u << 16); }
__device__ __forceinline__ ushort f2bu(float f) {
  union { bf16 b; ushort u; } cv; cv.b = __float2bfloat16(f); return cv.u;
}
__device__ __forceinline__ void gl_lds16(const ushort* g, ushort* l) {
  __builtin_amdgcn_global_load_lds((const __attribute__((address_space(1))) unsigned*)g,
                                   (__attribute__((address_space(3))) unsigned*)l, 16, 0, 0);
}
// tanh-form GELU via hw exp; |err vs erf-GELU| ~2e-4, below bf16 output quantization
__device__ __forceinline__ float fast_gelu(float x) {
  float z = 0.7978845608028654f * (x + 0.044715f * x * x * x);
  z = fmaxf(fminf(z, 10.f), -10.f);
  float e = __expf(2.f * z);
  float t = (e - 1.f) / (e + 1.f);
  return 0.5f * x * (1.f + t);
}

static constexpr int kT   = 4096;
static constexpr int kDim = 1024;
static constexpr float kScale   = 0.08838834764831845f;  // 1/sqrt(128)
static constexpr float kSelfVal = -5.0e4f;

// ---------------- dtype detector: bf16 vs fp32 inputs ----------------
__device__ __forceinline__ int sane_v(float f) { float a = fabsf(f); return (a > 1e-4f && a < 1e4f) ? 1 : 0; }

__global__ __launch_bounds__(256) void k_detect(const unsigned* __restrict__ x, int* __restrict__ flag) {
  __shared__ int cnt;
  int tid = threadIdx.x;
  if (tid == 0) cnt = 0;
  __syncthreads();
  int my = 0;
  const uint4* p = (const uint4*)x;
  for (int q = 0; q < 16; q++) {
    uint4 u = p[tid * 16 + q];
    my += sane_v(__uint_as_float(u.x << 16)) + sane_v(__uint_as_float(u.x & 0xffff0000u));
    my += sane_v(__uint_as_float(u.y << 16)) + sane_v(__uint_as_float(u.y & 0xffff0000u));
    my += sane_v(__uint_as_float(u.z << 16)) + sane_v(__uint_as_float(u.z & 0xffff0000u));
    my += sane_v(__uint_as_float(u.w << 16)) + sane_v(__uint_as_float(u.w & 0xffff0000u));
  }
  atomicAdd(&cnt, my);
  __syncthreads();
  if (tid == 0) flag[0] = (cnt >= 24576) ? 1 : 0;
}

__global__ __launch_bounds__(256) void k_cvt(const int* __restrict__ flag, const void* __restrict__ src,
                                             ushort* __restrict__ dst, int n) {
  int i = blockIdx.x * 256 + threadIdx.x;
  if (i >= n) return;
  dst[i] = (*flag) ? ((const ushort*)src)[i] : f2bu(((const float*)src)[i]);
}

__global__ __launch_bounds__(256) void k_init_any(const int* __restrict__ flag, const void* __restrict__ x,
                                                  float* __restrict__ x1, float* __restrict__ x2) {
  int i = blockIdx.x * 1024 + threadIdx.x * 4;
  float4 f;
  if (*flag) {
    ushort4 u = *(const ushort4*)((const ushort*)x + i);
    f.x = bu2f(u.x); f.y = bu2f(u.y); f.z = bu2f(u.z); f.w = bu2f(u.w);
  } else {
    f = *(const float4*)((const float*)x + i);
  }
  *(float4*)(x1 + i) = f;
  *(float4*)(x2 + i) = f;
}

__global__ __launch_bounds__(256) void k_final_any(const int* __restrict__ flag, const float* __restrict__ x1,
                                                   const float* __restrict__ x2, void* __restrict__ out) {
  int i = blockIdx.x * 1024 + threadIdx.x * 4;
  float4 a = *(const float4*)(x1 + i);
  float4 b = *(const float4*)(x2 + i);
  float4 s; s.x = a.x + b.x; s.y = a.y + b.y; s.z = a.z + b.z; s.w = a.w + b.w;
  if (*flag) {
    ushort4 u; u.x = f2bu(s.x); u.y = f2bu(s.y); u.z = f2bu(s.z); u.w = f2bu(s.w);
    *(ushort4*)((ushort*)out + i) = u;
  } else {
    *(float4*)((float*)out + i) = s;
  }
}

// ---------------- layernorm: fp32 in -> bf16 out ----------------
__global__ __launch_bounds__(256) void k_ln(const float* __restrict__ x, const ushort* __restrict__ g,
                                            const ushort* __restrict__ be, ushort* __restrict__ out) {
  __shared__ float ws[4], ws2[4];
  int row = blockIdx.x, tid = threadIdx.x;
  const float* xr = x + (size_t)row * kDim + tid * 4;
  float4 v = *(const float4*)xr;
  float s  = v.x + v.y + v.z + v.w;
  float s2 = v.x*v.x + v.y*v.y + v.z*v.z + v.w*v.w;
  #pragma unroll
  for (int off = 32; off; off >>= 1) { s += __shfl_down(s, off); s2 += __shfl_down(s2, off); }
  int wave = tid >> 6, lane = tid & 63;
  if (lane == 0) { ws[wave] = s; ws2[wave] = s2; }
  __syncthreads();
  s  = ws[0] + ws[1] + ws[2] + ws[3];
  s2 = ws2[0] + ws2[1] + ws2[2] + ws2[3];
  float mean = s * (1.f/1024.f);
  float var  = fmaxf(s2 * (1.f/1024.f) - mean*mean, 0.f);
  float rstd = rsqrtf(var + 1e-5f);
  int cb = tid * 4;
  ushort* o = out + (size_t)row * kDim + cb;
  o[0] = f2bu((v.x - mean) * rstd * bu2f(g[cb+0]) + bu2f(be[cb+0]));
  o[1] = f2bu((v.y - mean) * rstd * bu2f(g[cb+1]) + bu2f(be[cb+1]));
  o[2] = f2bu((v.z - mean) * rstd * bu2f(g[cb+2]) + bu2f(be[cb+2]));
  o[3] = f2bu((v.w - mean) * rstd * bu2f(g[cb+3]) + bu2f(be[cb+3]));
}

// ---------------- dual-dtype weight transpose: in[K,N] -> out[N,K] ----------------
__global__ __launch_bounds__(256) void k_transpose2(const int* __restrict__ flag, const void* __restrict__ src_bf,
                                                    const void* __restrict__ src_f, ushort* __restrict__ out,
                                                    int K, int N) {
  __shared__ ushort tile[32][33];
  int isbf = *flag;
  int nb = blockIdx.x * 32, kb = blockIdx.y * 32;
  int tx = threadIdx.x & 31, ty = threadIdx.x >> 5;
  for (int r = ty; r < 32; r += 8) {
    size_t idx = (size_t)(kb + r) * N + nb + tx;
    tile[r][tx] = isbf ? ((const ushort*)src_bf)[idx] : f2bu(((const float*)src_f)[idx]);
  }
  __syncthreads();
  for (int r = ty; r < 32; r += 8) out[(size_t)(nb + r) * K + kb + tx] = tile[tx][r];
}

// ---------------- rot transpose: rot[k=128][n=128] -> rotT[n=128][k=128] ----------------
__global__ __launch_bounds__(256) void k_rot_t(const ushort* __restrict__ rot, ushort* __restrict__ rotT) {
  int tid = threadIdx.x;
  for (int idx = tid; idx < 16384; idx += 256) {
    int n = idx >> 7, k = idx & 127;
    rotT[idx] = rot[k * 128 + n];
  }
}

// ---------------- k_gemm5<8>: 256x256 single-barrier pipelined GEMM (W1; round-7 proven) ----------------
// BN=256, BK=32, 512 thr = 8 waves (2M x 4N), BM=256 (wave tile 128x64). 4 LDS buffers
// (128 KB, 1 block/CU). __launch_bounds__(512,2) -> 256-reg budget: acc 8x4 + frags fit
// at VGPR=128 with ZERO spill (round-7 measured: 100 us, WRITE=output only).
// (Round-9 lesson: (512,4) caps VGPR at 128-
//  actual alloc 64 -> accumulator spill -> 2.3GB scratch writes, 7.5x slower. A 256^2
//  8-wave tile structurally cannot exceed 1 block/CU without spilling.)
// Phase kt: { 12 ds_read_b128 (buf kt&3) | stage kt+2 (4 gl_lds -> buf (kt+2)&3)
//   | setprio + 32 MFMA } -> vmcnt(4) -> s_barrier -> fence.
// RAW: wait at end of kt-1 leaves 4 (=kt+1's loads) -> tile kt landed; barrier publishes.
// WAR: stage target (kt+2)&3 = (kt-2)&3, last read in phase kt-2, >=2 barriers earlier.
// Tail stages are clamped dummies into dead buffers; vmcnt(0)+sync before epilogue.
// Swizzle: LDS slot s of row r holds global chunk s^((r>>1)&3); reads same XOR (free).
// mode 2 only here: Cb = bf16(gelu(A@B + bias)); LDS-bounce coalesced stores.
__global__ __launch_bounds__(512, 2) void k_gemm5w1(const ushort* __restrict__ A, const ushort* __restrict__ Bt,
                                                    const ushort* __restrict__ bias, ushort* __restrict__ Cb,
                                                    int M, int N, int K) {
  constexpr int BM = 256;
  __shared__ alignas(16) ushort SAu[4 * BM * 32];    // 64 KB
  __shared__ alignas(16) ushort SBu[4 * 256 * 32];   // 64 KB

  const int tid  = threadIdx.x;
  const int lane = tid & 63, wave = tid >> 6;
  const int lr = lane & 15, g = lane >> 4;
  const int wm = wave >> 2, wn = wave & 3;

  const int nbx = gridDim.x;
  const int nwg = nbx * gridDim.y;
  const int bid = blockIdx.y * nbx + blockIdx.x;
  const int swz = (bid & 7) * (nwg >> 3) + (bid >> 3);
  const int m0 = (swz / nbx) * BM;
  const int n0 = (swz % nbx) * 256;

  const int NT = K >> 5;

  // per-thread staging sources (global col-chunk pre-swizzled, LDS dest linear)
  const ushort* srcA[2];
  #pragma unroll
  for (int j = 0; j < 2; j++) {
    int chunk = wave * 128 + j * 64 + lane;
    int row = chunk >> 2, c = chunk & 3;
    int cs = c ^ ((row >> 1) & 3);
    srcA[j] = A + (size_t)(m0 + row) * K + cs * 8;
  }
  const ushort* srcB[2];
  #pragma unroll
  for (int j = 0; j < 2; j++) {
    int chunk = wave * 128 + j * 64 + lane;
    int row = chunk >> 2, c = chunk & 3;
    int cs = c ^ ((row >> 1) & 3);
    srcB[j] = Bt + (size_t)(n0 + row) * K + cs * 8;
  }

  int offA[8], offB[4];
  #pragma unroll
  for (int mi = 0; mi < 8; mi++) {
    int row = wm * 128 + mi * 16 + lr;
    offA[mi] = row * 32 + ((g ^ ((row >> 1) & 3)) * 8);
  }
  #pragma unroll
  for (int ni = 0; ni < 4; ni++) {
    int row = wn * 64 + ni * 16 + lr;
    offB[ni] = row * 32 + ((g ^ ((row >> 1) & 3)) * 8);
  }

  floatx4 acc[8][4];
  #pragma unroll
  for (int mi = 0; mi < 8; mi++)
    #pragma unroll
    for (int ni = 0; ni < 4; ni++) acc[mi][ni] = (floatx4){0.f, 0.f, 0.f, 0.f};

  // prologue: stage K-tiles 0,1
  #pragma unroll
  for (int p = 0; p < 2; p++) {
    #pragma unroll
    for (int j = 0; j < 2; j++) gl_lds16(srcA[j] + p * 32, SAu + p * (BM * 32) + (wave * 128 + j * 64) * 8);
    #pragma unroll
    for (int j = 0; j < 2; j++) gl_lds16(srcB[j] + p * 32, SBu + p * (256 * 32) + (wave * 128 + j * 64) * 8);
  }
  asm volatile("s_waitcnt vmcnt(4)" ::: "memory");
  __builtin_amdgcn_s_barrier();
  asm volatile("" ::: "memory");

  for (int kt = 0; kt < NT; kt++) {
    const ushort* sa = SAu + (kt & 3) * (BM * 32);
    const ushort* sb = SBu + (kt & 3) * (256 * 32);
    const int kp = ((kt + 2 < NT) ? (kt + 2) : 0) * 32;   // dummy-clamp past NT
    const int pb = (kt + 2) & 3;

    short8 a[8], b[4];
    #pragma unroll
    for (int mi = 0; mi < 8; mi++) a[mi] = *(const short8*)&sa[offA[mi]];
    #pragma unroll
    for (int ni = 0; ni < 4; ni++)  b[ni] = *(const short8*)&sb[offB[ni]];

    #pragma unroll
    for (int j = 0; j < 2; j++) gl_lds16(srcA[j] + kp, SAu + pb * (BM * 32) + (wave * 128 + j * 64) * 8);
    #pragma unroll
    for (int j = 0; j < 2; j++) gl_lds16(srcB[j] + kp, SBu + pb * (256 * 32) + (wave * 128 + j * 64) * 8);

    __builtin_amdgcn_s_setprio(1);
    #pragma unroll
    for (int mi = 0; mi < 8; mi++)
      #pragma unroll
      for (int ni = 0; ni < 4; ni++)
        acc[mi][ni] = __builtin_amdgcn_mfma_f32_16x16x32_bf16(a[mi], b[ni], acc[mi][ni], 0, 0, 0);
    __builtin_amdgcn_s_setprio(0);

    asm volatile("s_waitcnt vmcnt(4)" ::: "memory");   // tile kt+1 landed; kt+2 in flight
    __builtin_amdgcn_s_barrier();
    asm volatile("" ::: "memory");
  }

  asm volatile("s_waitcnt vmcnt(0)" ::: "memory");
  __syncthreads();

  const int hi4 = (lane >> 4) * 4;

  // LDS-bounce epilogue: acc -> swizzled LDS -> coalesced dwordx4 row stores
  ushort* reg0 = SAu;   // rows 0..127
  ushort* reg1 = SBu;   // rows 128..255
  #pragma unroll
  for (int mi = 0; mi < 8; mi++) {
    #pragma unroll
    for (int ni = 0; ni < 4; ni++) {
      int colw = wn * 64 + ni * 16 + lr;            // 0..255
      float bv = bu2f(bias[n0 + colw]);
      #pragma unroll
      for (int q = 0; q < 4; q++) {
        int grow = wm * 128 + mi * 16 + hi4 + q;    // 0..255
        ushort* reg = (grow < 128) ? reg0 : reg1;
        int rl = grow & 127;
        reg[rl * 256 + (((colw >> 3) ^ (rl & 7)) * 8) + (colw & 7)] = f2bu(fast_gelu(acc[mi][ni][q] + bv));
      }
    }
  }
  __syncthreads();
  {
    const int j = tid & 31;
    const int rsub = tid >> 5;     // 0..15
    #pragma unroll
    for (int p = 0; p < 16; p++) {
      int row = p * 16 + rsub;
      const ushort* reg = (row < 128) ? reg0 : reg1;
      int rl = row & 127;
      short8 v = *(const short8*)&reg[rl * 256 + ((j ^ (rl & 7)) * 8)];
      *(short8*)&Cb[(size_t)(m0 + row) * N + n0 + j * 8] = v;
    }
  }
  (void)M;
}

// ---------------- k_gemm6: occupancy-first pipelined GEMM (128^2, 3 blocks/CU) ----------------
// (round-8 proven; used for the N=1024 shapes and W2)
__global__ __launch_bounds__(256, 3) void k_gemm6(const ushort* __restrict__ A, const ushort* __restrict__ Bt,
                                                  const ushort* __restrict__ bias, float* __restrict__ Cf,
                                                  ushort* __restrict__ Cb, ushort* __restrict__ Cb2,
                                                  int M, int N, int K, int mode) {
  __shared__ alignas(16) ushort SAu[3 * 128 * 32];   // 24 KB
  __shared__ alignas(16) ushort SBu[3 * 128 * 32];   // 24 KB
  const int tid  = threadIdx.x;
  const int lane = tid & 63, wave = tid >> 6;        // 4 waves
  const int lr = lane & 15, g = lane >> 4;
  const int wm = wave >> 1, wn = wave & 1;

  const int nbx = gridDim.x;
  const int nwg = nbx * gridDim.y;
  const int bid = blockIdx.y * nbx + blockIdx.x;
  const int swz = (bid & 7) * (nwg >> 3) + (bid >> 3);
  const int m0 = (swz / nbx) * 128;
  const int n0 = (swz % nbx) * 128;
  const int NT = K >> 5;

  const ushort* srcA[2];
  const ushort* srcB[2];
  #pragma unroll
  for (int j = 0; j < 2; j++) {
    int chunk = wave * 128 + j * 64 + lane;          // 0..511
    int row = chunk >> 2, c = chunk & 3;
    int cs = c ^ ((row >> 1) & 3);
    srcA[j] = A  + (size_t)(m0 + row) * K + cs * 8;
    srcB[j] = Bt + (size_t)(n0 + row) * K + cs * 8;
  }

  int offA[4], offB[4];
  #pragma unroll
  for (int mi = 0; mi < 4; mi++) {
    int row = wm * 64 + mi * 16 + lr;
    offA[mi] = row * 32 + ((g ^ ((row >> 1) & 3)) * 8);
  }
  #pragma unroll
  for (int ni = 0; ni < 4; ni++) {
    int row = wn * 64 + ni * 16 + lr;
    offB[ni] = row * 32 + ((g ^ ((row >> 1) & 3)) * 8);
  }

  floatx4 acc[4][4];
  #pragma unroll
  for (int mi = 0; mi < 4; mi++)
    #pragma unroll
    for (int ni = 0; ni < 4; ni++) acc[mi][ni] = (floatx4){0.f, 0.f, 0.f, 0.f};

  // prologue: stage K-tiles 0,1
  #pragma unroll
  for (int p = 0; p < 2; p++) {
    #pragma unroll
    for (int j = 0; j < 2; j++) {
      gl_lds16(srcA[j] + p * 32, SAu + p * 4096 + (wave * 128 + j * 64) * 8);
      gl_lds16(srcB[j] + p * 32, SBu + p * 4096 + (wave * 128 + j * 64) * 8);
    }
  }
  asm volatile("s_waitcnt vmcnt(4)" ::: "memory");   // tile 0 landed
  __builtin_amdgcn_s_barrier();
  asm volatile("" ::: "memory");

  int cur = 0;
  for (int kt = 0; kt < NT; kt++) {
    const ushort* sa = SAu + cur * 4096;
    const ushort* sb = SBu + cur * 4096;
    int pb = cur + 2; if (pb >= 3) pb -= 3;
    const int kp = ((kt + 2 < NT) ? (kt + 2) : 0) * 32;   // dummy-clamp past NT

    short8 a[4], b[4];
    #pragma unroll
    for (int mi = 0; mi < 4; mi++) a[mi] = *(const short8*)&sa[offA[mi]];
    #pragma unroll
    for (int ni = 0; ni < 4; ni++) b[ni] = *(const short8*)&sb[offB[ni]];

    #pragma unroll
    for (int j = 0; j < 2; j++) {
      gl_lds16(srcA[j] + kp, SAu + pb * 4096 + (wave * 128 + j * 64) * 8);
      gl_lds16(srcB[j] + kp, SBu + pb * 4096 + (wave * 128 + j * 64) * 8);
    }

    __builtin_amdgcn_s_setprio(1);
    #pragma unroll
    for (int mi = 0; mi < 4; mi++)
      #pragma unroll
      for (int ni = 0; ni < 4; ni++)
        acc[mi][ni] = __builtin_amdgcn_mfma_f32_16x16x32_bf16(a[mi], b[ni], acc[mi][ni], 0, 0, 0);
    __builtin_amdgcn_s_setprio(0);

    asm volatile("s_waitcnt lgkmcnt(0)" ::: "memory");
    asm volatile("s_waitcnt vmcnt(4)" ::: "memory");   // tile kt+1 landed; kt+2 in flight
    __builtin_amdgcn_s_barrier();
    asm volatile("" ::: "memory");

    cur = (cur == 2) ? 0 : cur + 1;
  }

  asm volatile("s_waitcnt vmcnt(0)" ::: "memory");
  __syncthreads();

  const int hi4 = (lane >> 4) * 4;

  if (mode == 1) {
    #pragma unroll
    for (int mi = 0; mi < 4; mi++) {
      #pragma unroll
      for (int ni = 0; ni < 4; ni++) {
        int col = n0 + wn * 64 + ni * 16 + lr;
        float bv = bu2f(bias[col]);
        #pragma unroll
        for (int q = 0; q < 4; q++) {
          int r2 = m0 + wm * 64 + mi * 16 + hi4 + q;
          Cf[(size_t)r2 * N + col] += acc[mi][ni][q] + bv;
        }
      }
    }
  } else {
    #pragma unroll
    for (int mi = 0; mi < 4; mi++) {
      #pragma unroll
      for (int ni = 0; ni < 4; ni++) {
        int colw = wn * 64 + ni * 16 + lr;            // 0..127
        float bv = (mode == 2) ? bu2f(bias[n0 + colw]) : 0.f;
        #pragma unroll
        for (int q = 0; q < 4; q++) {
          int rl = wm * 64 + mi * 16 + hi4 + q;       // 0..127
          ushort* rowp = (rl < 96) ? (SBu + rl * 128) : (SAu + (rl - 96) * 128);
          float val = acc[mi][ni][q];
          ushort h = (mode == 2) ? f2bu(fast_gelu(val + bv)) : f2bu(val);
          rowp[(((colw >> 3) ^ (rl & 7)) * 8) + (colw & 7)] = h;
        }
      }
    }
    __syncthreads();
    {
      const int j = tid & 15;
      const int rsub = tid >> 4;     // 0..15
      #pragma unroll
      for (int p = 0; p < 8; p++) {
        int row = p * 16 + rsub;
        const ushort* rowp = (row < 96) ? (SBu + row * 128) : (SAu + (row - 96) * 128);
        short8 v = *(const short8*)&rowp[(j ^ (row & 7)) * 8];
        *(short8*)&Cb[(size_t)(m0 + row) * N + n0 + j * 8] = v;
      }
    }
    if (mode == 5) {
      __syncthreads();
      #pragma unroll
      for (int mi = 0; mi < 4; mi++) {
        #pragma unroll
        for (int ni = 0; ni < 4; ni++) {
          int colw = wn * 64 + ni * 16 + lr;
          #pragma unroll
          for (int q = 0; q < 4; q++) {
            int rl = wm * 64 + mi * 16 + hi4 + q;
            ushort* rowp = (rl < 96) ? (SBu + rl * 128) : (SAu + (rl - 96) * 128);
            float val = acc[mi][ni][q];
            ushort h = f2bu(val);
            rowp[(((colw >> 3) ^ (rl & 7)) * 8) + (colw & 7)] = f2bu(val - bu2f(h));
          }
        }
      }
      __syncthreads();
      const int j = tid & 15;
      const int rsub = tid >> 4;
      #pragma unroll
      for (int p = 0; p < 8; p++) {
        int row = p * 16 + rsub;
        const ushort* rowp = (row < 96) ? (SBu + row * 128) : (SAu + (row - 96) * 128);
        short8 v = *(const short8*)&rowp[(j ^ (row & 7)) * 8];
        *(short8*)&Cb2[(size_t)(m0 + row) * N + n0 + j * 8] = v;
      }
    }
  }
  (void)M;
}

// ---------------- MFMA bucket: consumes qk hi/lo bf16 planes; in-register first-max argmax ----------------
__global__ __launch_bounds__(256) void k_bucket_mfma(const ushort* __restrict__ qkh, const ushort* __restrict__ qkl,
                                                     const ushort* __restrict__ rotT, int* __restrict__ bkt) {
  __shared__ alignas(16) ushort Bs[128*128];  // rotT [n][k]  32 KB
  __shared__ alignas(16) ushort Ah[64*128];   // Q hi         16 KB
  __shared__ alignas(16) ushort Al[64*128];   // Q lo         16 KB
  const int tid = threadIdx.x;
  const int lane = tid & 63, wave = tid >> 6;
  const int lr = lane & 15, lk = (lane >> 4) * 8;
  const int tt = blockIdx.x * 64;
  const int bh = blockIdx.y;
  const int b = bh >> 3, hh = bh & 7;

  {
    int r = tid >> 2, c0 = (tid & 3) * 32;
    size_t base = ((size_t)(b * kT + tt + r)) * kDim + hh * 128 + c0;
    const uint4* sh = (const uint4*)(qkh + base);
    const uint4* sl = (const uint4*)(qkl + base);
    uint4* dh = (uint4*)&Ah[r * 128 + c0];
    uint4* dl = (uint4*)&Al[r * 128 + c0];
    #pragma unroll
    for (int i = 0; i < 4; i++) { dh[i] = sh[i]; dl[i] = sl[i]; }
  }
  {
    const uint4* src = (const uint4*)rotT;
    uint4* dst = (uint4*)Bs;
    for (int i = tid; i < 2048; i += 256) dst[i] = src[i];
  }
  __syncthreads();

  floatx4 acc[4][2];
  #pragma unroll
  for (int mi = 0; mi < 4; mi++) { acc[mi][0] = (floatx4){0,0,0,0}; acc[mi][1] = (floatx4){0,0,0,0}; }
  #pragma unroll
  for (int ks = 0; ks < 4; ks++) {
    short8 a[4], bb[2];
    #pragma unroll
    for (int ni = 0; ni < 2; ni++) bb[ni] = *(const short8*)&Bs[(wave*32 + ni*16 + lr)*128 + ks*32 + lk];
    #pragma unroll
    for (int mi = 0; mi < 4; mi++) a[mi] = *(const short8*)&Ah[(mi*16 + lr)*128 + ks*32 + lk];
    #pragma unroll
    for (int mi = 0; mi < 4; mi++)
      #pragma unroll
      for (int ni = 0; ni < 2; ni++)
        acc[mi][ni] = __builtin_amdgcn_mfma_f32_16x16x32_bf16(a[mi], bb[ni], acc[mi][ni], 0, 0, 0);
  }
  #pragma unroll
  for (int ks = 0; ks < 4; ks++) {
    short8 a[4], bb[2];
    #pragma unroll
    for (int ni = 0; ni < 2; ni++) bb[ni] = *(const short8*)&Bs[(wave*32 + ni*16 + lr)*128 + ks*32 + lk];
    #pragma unroll
    for (int mi = 0; mi < 4; mi++) a[mi] = *(const short8*)&Al[(mi*16 + lr)*128 + ks*32 + lk];
    #pragma unroll
    for (int mi = 0; mi < 4; mi++)
      #pragma unroll
      for (int ni = 0; ni < 2; ni++)
        acc[mi][ni] = __builtin_amdgcn_mfma_f32_16x16x32_bf16(a[mi], bb[ni], acc[mi][ni], 0, 0, 0);
  }

  #pragma unroll
  for (int mi = 0; mi < 4; mi++) {
    #pragma unroll
    for (int q = 0; q < 4; q++) {
      float v0 = acc[mi][0][q];
      float v1 = acc[mi][1][q];
      float best = v0; int bidx = lr;
      if (v1  > best) { best = v1;  bidx = 16 + lr; }
      if (-v0 > best) { best = -v0; bidx = 32 + lr; }
      if (-v1 > best) { best = -v1; bidx = 48 + lr; }
      #pragma unroll
      for (int m = 1; m <= 8; m <<= 1) {
        float ov = __shfl_xor(best, m);
        int   oi = __shfl_xor(bidx, m);
        if (ov > best || (ov == best && oi < bidx)) { best = ov; bidx = oi; }
      }
      if (lr == 0) {
        int row = mi*16 + ((lane >> 4) & 3)*4 + q;
        bkt[(bh*4 + wave)*4096 + tt + row] = bidx;
      }
    }
  }
}

// ---------------- stable counting sort per (bh,hash) ----------------
__global__ __launch_bounds__(256) void k_sort(const int* __restrict__ bkt, int* __restrict__ st) {
  __shared__ unsigned char  hist[64*256];
  __shared__ unsigned short offs[64*256];
  __shared__ int base[64];
  int tid = threadIdx.x, grp = blockIdx.x;
  const int* bk = bkt + grp * 4096;
  for (int i = tid; i < 64*256; i += 256) hist[i] = 0;
  __syncthreads();
  int myb[16];
  #pragma unroll
  for (int j = 0; j < 16; j++) {
    myb[j] = bk[tid*16 + j];
    hist[myb[j]*256 + tid] += 1;
  }
  __syncthreads();
  if (tid < 64) {
    int run = 0;
    for (int t = 0; t < 256; t++) { offs[tid*256 + t] = (unsigned short)run; run += hist[tid*256 + t]; }
    base[tid] = run;
  }
  __syncthreads();
  if (tid == 0) {
    int run = 0;
    for (int b2 = 0; b2 < 64; b2++) { int c = base[b2]; base[b2] = run; run += c; }
  }
  __syncthreads();
  #pragma unroll
  for (int j = 0; j < 16; j++) {
    int b2 = myb[j];
    int r = 0;
    for (int jj = 0; jj < j; jj++) r += (myb[jj] == b2) ? 1 : 0;
    st[grp*4096 + base[b2] + (int)offs[b2*256 + tid] + r] = tid*16 + j;
  }
}

// ---------------- chunked LSH attention (bf16 qk hi-plane input) ----------------
__global__ __launch_bounds__(256) void k_attn(const ushort* __restrict__ qkh, const ushort* __restrict__ vbuf,
                                              const int* __restrict__ st, ushort* __restrict__ o_r,
                                              float* __restrict__ lse_r) {
  __shared__ alignas(16) ushort KV[128*136];
  __shared__ alignas(16) ushort Ps[64*136];
  __shared__ float rnorm[128];
  __shared__ int   kposs[128];
  __shared__ float red1[64*4];
  __shared__ float red2[64*4];
  __shared__ float lrow[64];

  const int tid = threadIdx.x;
  const int bid = blockIdx.x;
  const int bh = bid >> 8;
  const int c  = bid & 255;
  const int h  = c >> 6;
  const int cprev = (c + 255) & 255;
  const int b  = bh >> 3, hh = bh & 7;
  const int lane = tid & 63, wave = tid >> 6;
  const int lr = lane & 15, lk = (lane >> 4) * 8;

  {
    int j = tid >> 1, half = tid & 1;
    int slot = (j < 64) ? (c*64 + j) : (cprev*64 + (j - 64));
    int pos = st[bh*16384 + slot];
    if (half == 0) kposs[j] = pos;
    const ushort* src = qkh + ((size_t)(b * kT + pos)) * kDim + hh*128 + half*64;
    float ss = 0.f;
    #pragma unroll
    for (int i2 = 0; i2 < 64; i2 += 8) {
      uint4 u = *(const uint4*)(src + i2);
      *(uint4*)&KV[j*136 + half*64 + i2] = u;
      float f0 = bu2f((ushort)(u.x & 0xffffu)), f1 = bu2f((ushort)(u.x >> 16));
      float f2 = bu2f((ushort)(u.y & 0xffffu)), f3 = bu2f((ushort)(u.y >> 16));
      float f4 = bu2f((ushort)(u.z & 0xffffu)), f5 = bu2f((ushort)(u.z >> 16));
      float f6 = bu2f((ushort)(u.w & 0xffffu)), f7 = bu2f((ushort)(u.w >> 16));
      ss += f0*f0 + f1*f1 + f2*f2 + f3*f3 + f4*f4 + f5*f5 + f6*f6 + f7*f7;
    }
    ss += __shfl_xor(ss, 1);
    if (half == 0) rnorm[j] = 1.f / fmaxf(sqrtf(ss), 1e-12f);
  }
  __syncthreads();

  {
    floatx4 acc[4][2];
    #pragma unroll
    for (int mi = 0; mi < 4; mi++) { acc[mi][0] = (floatx4){0,0,0,0}; acc[mi][1] = (floatx4){0,0,0,0}; }
    #pragma unroll
    for (int ks = 0; ks < 4; ks++) {
      short8 a[4], bb[2];
      #pragma unroll
      for (int mi = 0; mi < 4; mi++) a[mi]  = *(const short8*)&KV[(mi*16 + lr)*136 + ks*32 + lk];
      #pragma unroll
      for (int ni = 0; ni < 2; ni++) bb[ni] = *(const short8*)&KV[(wave*32 + ni*16 + lr)*136 + ks*32 + lk];
      #pragma unroll
      for (int mi = 0; mi < 4; mi++)
        #pragma unroll
        for (int ni = 0; ni < 2; ni++)
          acc[mi][ni] = __builtin_amdgcn_mfma_f32_16x16x32_bf16(a[mi], bb[ni], acc[mi][ni], 0, 0, 0);
    }
    #pragma unroll
    for (int mi = 0; mi < 4; mi++) {
      #pragma unroll
      for (int ni = 0; ni < 2; ni++) {
        int col = wave*32 + ni*16 + lr;
        float rn = rnorm[col] * kScale;
        int cpos = kposs[col];
        #pragma unroll
        for (int q = 0; q < 4; q++) {
          int row = mi*16 + (lane >> 4)*4 + q;
          float val = acc[mi][ni][q] * rn;
          if (cpos == kposs[row]) val = kSelfVal;
          Ps[row*136 + col] = f2bu(val);
        }
      }
    }
  }
  __syncthreads();

  {
    int j = tid >> 1, half = tid & 1;
    int pos = kposs[j];
    const ushort* src = vbuf + ((size_t)(b * kT + pos)) * kDim + hh*128 + half*64;
    #pragma unroll
    for (int i2 = 0; i2 < 64; i2 += 8) {
      uint4 u = *(const uint4*)(src + i2);
      int d0 = half*64 + i2;
      KV[(d0+0)*136 + j] = (ushort)(u.x & 0xffffu); KV[(d0+1)*136 + j] = (ushort)(u.x >> 16);
      KV[(d0+2)*136 + j] = (ushort)(u.y & 0xffffu); KV[(d0+3)*136 + j] = (ushort)(u.y >> 16);
      KV[(d0+4)*136 + j] = (ushort)(u.z & 0xffffu); KV[(d0+5)*136 + j] = (ushort)(u.z >> 16);
      KV[(d0+6)*136 + j] = (ushort)(u.w & 0xffffu); KV[(d0+7)*136 + j] = (ushort)(u.w >> 16);
    }
  }

  {
    int i = tid >> 2, part = tid & 3;
    const int jb = part * 32;
    float m = -1e30f;
    for (int j2 = 0; j2 < 32; j2++) m = fmaxf(m, bu2f(Ps[i*136 + jb + j2]));
    red1[i*4 + part] = m;
    __syncthreads();
    m = fmaxf(fmaxf(red1[i*4+0], red1[i*4+1]), fmaxf(red1[i*4+2], red1[i*4+3]));
    float ssum = 0.f;
    for (int j2 = 0; j2 < 32; j2++) {
      float arg = fmaxf(fminf(bu2f(Ps[i*136 + jb + j2]) - m, 0.f), -80.f);
      float p = __expf(arg);
      ssum += p;
      Ps[i*136 + jb + j2] = f2bu(p);
    }
    red2[i*4 + part] = ssum;
    __syncthreads();
    if (part == 0) {
      float l = fmaxf(red2[i*4+0] + red2[i*4+1] + red2[i*4+2] + red2[i*4+3], 1e-20f);
      lrow[i] = 1.f / l;
      lse_r[(size_t)(bh*4 + h)*4096 + kposs[i]] = m + __logf(l);
    }
  }
  __syncthreads();

  {
    floatx4 acc[4][2];
    #pragma unroll
    for (int mi = 0; mi < 4; mi++) { acc[mi][0] = (floatx4){0,0,0,0}; acc[mi][1] = (floatx4){0,0,0,0}; }
    #pragma unroll
    for (int ks = 0; ks < 4; ks++) {
      short8 a[4], bb[2];
      #pragma unroll
      for (int mi = 0; mi < 4; mi++) a[mi]  = *(const short8*)&Ps[(mi*16 + lr)*136 + ks*32 + lk];
      #pragma unroll
      for (int ni = 0; ni < 2; ni++) bb[ni] = *(const short8*)&KV[(wave*32 + ni*16 + lr)*136 + ks*32 + lk];
      #pragma unroll
      for (int mi = 0; mi < 4; mi++)
        #pragma unroll
        for (int ni = 0; ni < 2; ni++)
          acc[mi][ni] = __builtin_amdgcn_mfma_f32_16x16x32_bf16(a[mi], bb[ni], acc[mi][ni], 0, 0, 0);
    }
    #pragma unroll
    for (int mi = 0; mi < 4; mi++) {
      #pragma unroll
      for (int ni = 0; ni < 2; ni++) {
        int d = wave*32 + ni*16 + lr;
        #pragma unroll
        for (int q = 0; q < 4; q++) {
          int row = mi*16 + (lane >> 4)*4 + q;
          float o = acc[mi][ni][q] * lrow[row];
          o_r[((size_t)(bh*4 + h)*4096 + kposs[row])*128 + d] = f2bu(o);
        }
      }
    }
  }
}

// ---------------- combine hash rounds ----------------
__global__ __launch_bounds__(256) void k_combine(const ushort* __restrict__ o_r, const float* __restrict__ lse_r,
                                                 ushort* __restrict__ attnbf) {
  int rid = blockIdx.x * 2 + (threadIdx.x >> 7);
  int d = threadIdx.x & 127;
  int bh = rid >> 12, t = rid & 4095;
  int b = bh >> 3, hh = bh & 7;
  size_t base = (size_t)bh * 16384 + t;
  float l0 = lse_r[base], l1 = lse_r[base + 4096], l2 = lse_r[base + 8192], l3 = lse_r[base + 12288];
  float M = fmaxf(fmaxf(l0, l1), fmaxf(l2, l3));
  float e0 = __expf(fmaxf(fminf(l0 - M, 0.f), -80.f));
  float e1 = __expf(fmaxf(fminf(l1 - M, 0.f), -80.f));
  float e2 = __expf(fmaxf(fminf(l2 - M, 0.f), -80.f));
  float e3 = __expf(fmaxf(fminf(l3 - M, 0.f), -80.f));
  float inv = 1.f / (e0 + e1 + e2 + e3);
  float o = e0 * bu2f(o_r[(base         )*128 + d]) + e1 * bu2f(o_r[(base +  4096)*128 + d])
          + e2 * bu2f(o_r[(base +  8192)*128 + d]) + e3 * bu2f(o_r[(base + 12288)*128 + d]);
  attnbf[((size_t)b * kT + t) * kDim + hh*128 + d] = f2bu(o * inv);
}

extern "C" void kernel_launch(void* const* d_in, const int* in_sizes, int n_in,
                              void* d_out, int out_size, void* d_ws, size_t ws_size,
                              hipStream_t stream) {
  (void)in_sizes; (void)n_in; (void)out_size; (void)ws_size;
  const void* x     = d_in[0];
  const void* ln1_g = d_in[1];
  const void* ln1_b = d_in[2];
  const void* Wqk   = d_in[3];
  const void* Wv    = d_in[4];
  const void* Wo    = d_in[5];
  const void* bo    = d_in[6];
  const void* ln2_g = d_in[7];
  const void* ln2_b = d_in[8];
  const void* W1    = d_in[9];
  const void* b1    = d_in[10];
  const void* W2    = d_in[11];
  const void* b2    = d_in[12];
  const void* rot   = d_in[13];

  char* w = (char*)d_ws;
  int*    flag = (int*)w;    w += 256;
  ushort* prm  = (ushort*)w; w += 131072;
  float* x1  = (float*)w;  w += 33554432;
  float* x2  = (float*)w;  w += 33554432;
  ushort* qkh = (ushort*)w; w += 16777216;
  ushort* qkl = (ushort*)w; w += 16777216;
  ushort* vbb = (ushort*)w; w += 16777216;
  ushort* xbf = (ushort*)w; w += 16777216;
  ushort* orb = (ushort*)w; w += 67108864;
  float* lse = (float*)w;  w += 1048576;
  int*   bkt = (int*)w;    w += 1048576;
  int*   stb = (int*)w;    w += 1048576;
  ushort* wtA = (ushort*)w; w += 2097152;
  ushort* wtB = (ushort*)w; w += 2097152;
  ushort* wtC = (ushort*)w; w += 2097152;
  ushort* wt1 = (ushort*)w; w += 8388608;
  ushort* wt2 = (ushort*)w; w += 8388608;
  ushort* rtT = (ushort*)w; w += 32768;

  ushort* pLN1G = prm + 0;     ushort* pLN1B = prm + 2048;
  ushort* pBO   = prm + 4096;  ushort* pLN2G = prm + 6144;
  ushort* pLN2B = prm + 8192;  ushort* pB1   = prm + 10240;
  ushort* pB2   = prm + 18432; ushort* pROT  = prm + 20480;

  k_detect<<<1, 256, 0, stream>>>((const unsigned*)x, flag);
  k_cvt<<<8,   256, 0, stream>>>(flag, ln1_g, pLN1G, 2048);
  k_cvt<<<8,   256, 0, stream>>>(flag, ln1_b, pLN1B, 2048);
  k_cvt<<<8,   256, 0, stream>>>(flag, bo,    pBO,   2048);
  k_cvt<<<8,   256, 0, stream>>>(flag, ln2_g, pLN2G, 2048);
  k_cvt<<<8,   256, 0, stream>>>(flag, ln2_b, pLN2B, 2048);
  k_cvt<<<32,  256, 0, stream>>>(flag, b1,    pB1,   8192);
  k_cvt<<<8,   256, 0, stream>>>(flag, b2,    pB2,   2048);
  k_cvt<<<128, 256, 0, stream>>>(flag, rot,   pROT,  32768);
  k_init_any<<<8192, 256, 0, stream>>>(flag, x, x1, x2);

  for (int d = 0; d < 2; d++) {
    k_transpose2<<<dim3(32, 32),  256, 0, stream>>>(flag,
        (const char*)Wqk + (size_t)d*1048576*2, (const char*)Wqk + (size_t)d*1048576*4, wtA, 1024, 1024);
    k_transpose2<<<dim3(32, 32),  256, 0, stream>>>(flag,
        (const char*)Wv  + (size_t)d*1048576*2, (const char*)Wv  + (size_t)d*1048576*4, wtB, 1024, 1024);
    k_transpose2<<<dim3(32, 32),  256, 0, stream>>>(flag,
        (const char*)Wo  + (size_t)d*1048576*2, (const char*)Wo  + (size_t)d*1048576*4, wtC, 1024, 1024);
    k_transpose2<<<dim3(128, 32), 256, 0, stream>>>(flag,
        (const char*)W1  + (size_t)d*4194304*2, (const char*)W1  + (size_t)d*4194304*4, wt1, 1024, 4096);
    k_transpose2<<<dim3(32, 128), 256, 0, stream>>>(flag,
        (const char*)W2  + (size_t)d*4194304*2, (const char*)W2  + (size_t)d*4194304*4, wt2, 4096, 1024);
    k_rot_t<<<1, 256, 0, stream>>>(pROT + (size_t)d * 16384, rtT);

    k_ln<<<8192, 256, 0, stream>>>(x2, pLN1G + d*1024, pLN1B + d*1024, xbf);
    k_gemm6<<<dim3(8, 64), 256, 0, stream>>>(xbf, wtA, nullptr, nullptr, qkh, qkl, 8192, 1024, 1024, 5);
    k_gemm6<<<dim3(8, 64), 256, 0, stream>>>(xbf, wtB, nullptr, nullptr, vbb, nullptr, 8192, 1024, 1024, 3);
    k_bucket_mfma<<<dim3(64, 16), 256, 0, stream>>>(qkh, qkl, rtT, bkt);
    k_sort<<<64, 256, 0, stream>>>(bkt, stb);
    k_attn<<<4096, 256, 0, stream>>>(qkh, vbb, stb, orb, lse);
    k_combine<<<32768, 256, 0, stream>>>(orb, lse, xbf);
    k_gemm6<<<dim3(8, 64), 256, 0, stream>>>(xbf, wtC, pBO + d*1024, x1, nullptr, nullptr, 8192, 1024, 1024, 1);
    k_ln<<<8192, 256, 0, stream>>>(x1, pLN2G + d*1024, pLN2B + d*1024, xbf);
    k_gemm5w1<<<dim3(16, 32), 512, 0, stream>>>(xbf, wt1, pB1 + d*4096, orb, 8192, 4096, 1024);
    k_gemm6<<<dim3(8, 64), 256, 0, stream>>>(orb, wt2, pB2 + d*1024, x2, nullptr, nullptr, 8192, 1024, 4096, 1);
  }
  k_final_any<<<8192, 256, 0, stream>>>(flag, x1, x2, d_out);
}